// Round 1
// baseline (2593.379 us; speedup 1.0000x reference)
//
#include <hip/hip_runtime.h>
#include <hip/hip_bf16.h>
#include <math.h>

// GRU decoder w/ attention. f32 baseline, restructured:
//  - Wfused = Wo @ W_ih[:,512:].T precomputed (removes attn_out GEMM from chain)
//  - giE[t] = emb_t @ W_ih[:,:512].T precomputed for all t (batched)
//  - logits batched after the scan (1280x32000x512, one GEMM)
//  - per-step: q(splitK) -> attn -> giC(splitK) -> gate_ln   (+ gh splitK)
// Dims: B=64 N=49 ENC=2048 D=A=512 H=8 hd=64 T=20 V=32000 G3=1536

#define TSTEPS 20

// ---------------- ws layout (float offsets) ----------------
#define OFF_ME      0u          // 64*2048
#define OFF_EMBALL  131072u     // 1280*512
#define OFF_KT      786432u     // 64*8*64*49
#define OFF_V       2392064u    // 3136*512
#define OFF_GIE     3997696u    // 1280*1536
#define OFF_WF      5963776u    // 512*1536
#define OFF_GIBO    6750208u    // 1536
#define OFF_H       6751744u    // 64*512
#define OFF_HALL    6784512u    // 1280*512
#define OFF_H0P     7439872u    // 8*64*512
#define OFF_QP      7702016u    // 4*64*512
#define OFF_GHP     7833088u    // 4*64*1536
#define OFF_GIP     8226304u    // 4*64*1536
#define OFF_CTX     8619520u    // 64*512

// mean over N=49 of encoder outputs
__global__ void mean_kernel(const float* __restrict__ enc, float* __restrict__ me) {
    int i = blockIdx.x * 256 + threadIdx.x;       // 64*2048
    int b = i >> 11, e = i & 2047;
    const float* p = enc + (size_t)b * 49 * 2048 + e;
    float s = 0.f;
    #pragma unroll 7
    for (int n = 0; n < 49; n++) s += p[n * 2048];
    me[i] = s * (1.0f / 49.0f);
}

// gather embeddings for all (t,b) + zero the attention-weight output region
__global__ void init_kernel(const int* __restrict__ captions, const float* __restrict__ emb_w,
                            float* __restrict__ embAll, float* __restrict__ attw) {
    int i = blockIdx.x * 256 + threadIdx.x;       // 1280*512
    int t = i >> 15;
    int b = (i >> 9) & 63;
    int e = i & 511;
    int tok = captions[b * 21 + t];
    embAll[i] = emb_w[(size_t)tok * 512 + e];
    if (i < 62720) attw[i] = 0.f;
}

// gibo[j] = sum_e W_ih[j][512+e] * bo[e]
__global__ void gibo_kernel(const float* __restrict__ W_ih, const float* __restrict__ bo,
                            float* __restrict__ gibo) {
    int j = blockIdx.x, tid = threadIdx.x;        // 1536 blocks x 256
    const float* w = W_ih + (size_t)j * 2560 + 512;
    float s = 0.f;
    for (int e = tid; e < 2048; e += 256) s += w[e] * bo[e];
    for (int o = 32; o; o >>= 1) s += __shfl_xor(s, o);
    __shared__ float r[4];
    if ((tid & 63) == 0) r[tid >> 6] = s;
    __syncthreads();
    if (tid == 0) gibo[j] = r[0] + r[1] + r[2] + r[3];
}

// M=64 split-K GEMM: Cp[kz][64][N] = A[64, kslice] * B ; bt=0: B[k][n], bt=1: B[n][k]
__global__ __launch_bounds__(256) void gemm_splitk(
    const float* __restrict__ A, int lda,
    const float* __restrict__ Bm, int ldb, int bt,
    float* __restrict__ Cp, int N, int KC) {
    __shared__ float As[16][68];
    __shared__ float Bs[16][68];
    int tid = threadIdx.x;
    int n0 = blockIdx.x * 64;
    int k0base = blockIdx.y * KC;
    int tn = tid & 15, tm = tid >> 4;
    float acc[4][4] = {};
    int am = tid >> 2, akq = (tid & 3) * 4;
    for (int kk = 0; kk < KC; kk += 16) {
        int k0 = k0base + kk;
        float4 av = *(const float4*)(A + (size_t)am * lda + k0 + akq);
        if (bt == 0) {
            int bk = tid >> 4, bn = (tid & 15) * 4;
            float4 bv = *(const float4*)(Bm + (size_t)(k0 + bk) * ldb + n0 + bn);
            *(float4*)&Bs[bk][bn] = bv;
        } else {
            int bn = tid >> 2, bkq = (tid & 3) * 4;
            float4 bv = *(const float4*)(Bm + (size_t)(n0 + bn) * ldb + k0 + bkq);
            Bs[bkq + 0][bn] = bv.x; Bs[bkq + 1][bn] = bv.y;
            Bs[bkq + 2][bn] = bv.z; Bs[bkq + 3][bn] = bv.w;
        }
        As[akq + 0][am] = av.x; As[akq + 1][am] = av.y;
        As[akq + 2][am] = av.z; As[akq + 3][am] = av.w;
        __syncthreads();
        #pragma unroll
        for (int k = 0; k < 16; k++) {
            float4 a4 = *(const float4*)&As[k][tm * 4];
            float4 b4 = *(const float4*)&Bs[k][tn * 4];
            float a_[4] = {a4.x, a4.y, a4.z, a4.w};
            float b_[4] = {b4.x, b4.y, b4.z, b4.w};
            #pragma unroll
            for (int i = 0; i < 4; i++)
                #pragma unroll
                for (int j = 0; j < 4; j++) acc[i][j] += a_[i] * b_[j];
        }
        __syncthreads();
    }
    float* cp = Cp + (size_t)blockIdx.y * 64 * N + n0;
    #pragma unroll
    for (int i = 0; i < 4; i++) {
        float4 o = make_float4(acc[i][0], acc[i][1], acc[i][2], acc[i][3]);
        *(float4*)(cp + (size_t)(tm * 4 + i) * N + tn * 4) = o;
    }
}

// 128x128-tile GEMM, 8x8 per thread. bt as above. emode: 0 plain(+bias), 1 logits
// scatter ((t*64+b) row -> (b*20+t)), 2 kt scatter (row=b*49+nn, col=h*64+d).
__global__ __launch_bounds__(256) void gemm128(
    const float* __restrict__ A, int lda, int M,
    const float* __restrict__ Bm, int ldb, int bt,
    const float* __restrict__ bias,
    float* __restrict__ C, int ldc, int K, int emode) {
    __shared__ float As[16][136];
    __shared__ float Bs[16][136];
    int tid = threadIdx.x;
    int n0 = blockIdx.x * 128, m0 = blockIdx.y * 128;
    int tn = tid & 15, tm = tid >> 4;
    float acc[8][8] = {};
    for (int k0 = 0; k0 < K; k0 += 16) {
        {
            int m = tid >> 1, kq = (tid & 1) * 8;
            int gm = m0 + m;
            float4 v0 = make_float4(0, 0, 0, 0), v1 = make_float4(0, 0, 0, 0);
            if (gm < M) {
                v0 = *(const float4*)(A + (size_t)gm * lda + k0 + kq);
                v1 = *(const float4*)(A + (size_t)gm * lda + k0 + kq + 4);
            }
            As[kq + 0][m] = v0.x; As[kq + 1][m] = v0.y; As[kq + 2][m] = v0.z; As[kq + 3][m] = v0.w;
            As[kq + 4][m] = v1.x; As[kq + 5][m] = v1.y; As[kq + 6][m] = v1.z; As[kq + 7][m] = v1.w;
        }
        if (bt) {
            int n = tid >> 1, kq = (tid & 1) * 8;
            float4 v0 = *(const float4*)(Bm + (size_t)(n0 + n) * ldb + k0 + kq);
            float4 v1 = *(const float4*)(Bm + (size_t)(n0 + n) * ldb + k0 + kq + 4);
            Bs[kq + 0][n] = v0.x; Bs[kq + 1][n] = v0.y; Bs[kq + 2][n] = v0.z; Bs[kq + 3][n] = v0.w;
            Bs[kq + 4][n] = v1.x; Bs[kq + 5][n] = v1.y; Bs[kq + 6][n] = v1.z; Bs[kq + 7][n] = v1.w;
        } else {
            int bk = tid >> 4, n8 = (tid & 15) * 8;
            float4 v0 = *(const float4*)(Bm + (size_t)(k0 + bk) * ldb + n0 + n8);
            float4 v1 = *(const float4*)(Bm + (size_t)(k0 + bk) * ldb + n0 + n8 + 4);
            *(float4*)&Bs[bk][n8] = v0;
            *(float4*)&Bs[bk][n8 + 4] = v1;
        }
        __syncthreads();
        #pragma unroll
        for (int k = 0; k < 16; k++) {
            float4 a0 = *(const float4*)&As[k][tm * 8];
            float4 a1 = *(const float4*)&As[k][tm * 8 + 4];
            float4 b0 = *(const float4*)&Bs[k][tn * 4];
            float4 b1 = *(const float4*)&Bs[k][64 + tn * 4];
            float a_[8] = {a0.x, a0.y, a0.z, a0.w, a1.x, a1.y, a1.z, a1.w};
            float b_[8] = {b0.x, b0.y, b0.z, b0.w, b1.x, b1.y, b1.z, b1.w};
            #pragma unroll
            for (int i = 0; i < 8; i++)
                #pragma unroll
                for (int j = 0; j < 8; j++) acc[i][j] += a_[i] * b_[j];
        }
        __syncthreads();
    }
    // columns: j<4 -> n0+tn*4+j ; j>=4 -> n0+64+tn*4+(j-4)
    float bvals[8];
    #pragma unroll
    for (int j = 0; j < 8; j++) {
        int col = (j < 4) ? (n0 + tn * 4 + j) : (n0 + 64 + tn * 4 + j - 4);
        bvals[j] = bias ? bias[col] : 0.f;
    }
    #pragma unroll
    for (int i = 0; i < 8; i++) {
        int gm = m0 + tm * 8 + i;
        if (gm >= M) break;
        if (emode == 0) {
            float* cp = C + (size_t)gm * ldc;
            float4 o0 = make_float4(acc[i][0] + bvals[0], acc[i][1] + bvals[1],
                                    acc[i][2] + bvals[2], acc[i][3] + bvals[3]);
            float4 o1 = make_float4(acc[i][4] + bvals[4], acc[i][5] + bvals[5],
                                    acc[i][6] + bvals[6], acc[i][7] + bvals[7]);
            *(float4*)(cp + n0 + tn * 4) = o0;
            *(float4*)(cp + n0 + 64 + tn * 4) = o1;
        } else if (emode == 1) {
            int orow = (gm & 63) * TSTEPS + (gm >> 6);
            float* cp = C + (size_t)orow * ldc;
            float4 o0 = make_float4(acc[i][0] + bvals[0], acc[i][1] + bvals[1],
                                    acc[i][2] + bvals[2], acc[i][3] + bvals[3]);
            float4 o1 = make_float4(acc[i][4] + bvals[4], acc[i][5] + bvals[5],
                                    acc[i][6] + bvals[6], acc[i][7] + bvals[7]);
            *(float4*)(cp + n0 + tn * 4) = o0;
            *(float4*)(cp + n0 + 64 + tn * 4) = o1;
        } else { // kt scatter
            int bb = gm / 49, nn2 = gm - bb * 49;
            #pragma unroll
            for (int j = 0; j < 8; j++) {
                int col = (j < 4) ? (n0 + tn * 4 + j) : (n0 + 64 + tn * 4 + j - 4);
                int hh = col >> 6, dd = col & 63;
                C[((size_t)(bb * 8 + hh) * 64 + dd) * 49 + nn2] = acc[i][j] + bvals[j];
            }
        }
    }
}

__global__ void reduce_h0(const float* __restrict__ h0p, const float* __restrict__ init_b,
                          float* __restrict__ h) {
    int i = blockIdx.x * 256 + threadIdx.x;  // 32768
    float s = init_b[i & 511];
    #pragma unroll
    for (int z = 0; z < 8; z++) s += h0p[z * 32768 + i];
    h[i] = s;
}

// one block per (b,h); 64 threads
__global__ void attn_kernel(const float* __restrict__ qp, const float* __restrict__ bq,
                            const float* __restrict__ kt, const float* __restrict__ v,
                            float* __restrict__ ctx, float* __restrict__ attw, int t) {
    int bh = blockIdx.x;
    int b = bh >> 3, hh = bh & 7;
    int lane = threadIdx.x;
    __shared__ float qs[64];
    __shared__ float al[49];
    float qv = bq[hh * 64 + lane];
    #pragma unroll
    for (int s = 0; s < 4; s++) qv += qp[s * 32768 + b * 512 + hh * 64 + lane];
    qs[lane] = qv;
    __syncthreads();
    float sc = -1e30f;
    if (lane < 49) {
        const float* kp = kt + (size_t)bh * 64 * 49 + lane;
        float a = 0.f;
        #pragma unroll 8
        for (int d = 0; d < 64; d++) a += qs[d] * kp[d * 49];
        sc = a * 0.125f;
    }
    float mx = sc;
    for (int o = 32; o; o >>= 1) mx = fmaxf(mx, __shfl_xor(mx, o));
    float e = (lane < 49) ? expf(sc - mx) : 0.f;
    float sm = e;
    for (int o = 32; o; o >>= 1) sm += __shfl_xor(sm, o);
    float a = e / sm;
    if (lane < 49) {
        al[lane] = a;
        atomicAdd(&attw[(size_t)(b * TSTEPS + t) * 49 + lane], a * 0.125f);
    }
    __syncthreads();
    const float* vp = v + (size_t)b * 49 * 512 + hh * 64 + lane;
    float c = 0.f;
    #pragma unroll 7
    for (int n = 0; n < 49; n++) c += al[n] * vp[n * 512];
    ctx[b * 512 + hh * 64 + lane] = c;
}

// GRU gates + LayerNorm. one block per batch, 512 threads
__global__ void gate_ln_kernel(const float* __restrict__ gip, const float* __restrict__ ghp,
                               const float* __restrict__ giE, const float* __restrict__ gibo,
                               const float* __restrict__ b_ih, const float* __restrict__ b_hh,
                               const float* __restrict__ ln_g, const float* __restrict__ ln_b,
                               float* __restrict__ h, float* __restrict__ h_all, int t) {
    int b = blockIdx.x, d = threadIdx.x;
    const float* gie = giE + (size_t)(t * 64 + b) * 1536;
    float g0 = b_ih[d] + gibo[d] + gie[d];
    float g1 = b_ih[512 + d] + gibo[512 + d] + gie[512 + d];
    float g2 = b_ih[1024 + d] + gibo[1024 + d] + gie[1024 + d];
    float e0 = b_hh[d], e1 = b_hh[512 + d], e2 = b_hh[1024 + d];
    #pragma unroll
    for (int s = 0; s < 4; s++) {
        const float* gp = gip + (size_t)s * 98304 + b * 1536;
        const float* hp = ghp + (size_t)s * 98304 + b * 1536;
        g0 += gp[d]; g1 += gp[512 + d]; g2 += gp[1024 + d];
        e0 += hp[d]; e1 += hp[512 + d]; e2 += hp[1024 + d];
    }
    float r = 1.f / (1.f + expf(-(g0 + e0)));
    float z = 1.f / (1.f + expf(-(g1 + e1)));
    float nn = tanhf(g2 + r * e2);
    float hprev = h[b * 512 + d];
    float hn = (1.f - z) * nn + z * hprev;
    __shared__ float red[8];
    float x = hn;
    for (int o = 32; o; o >>= 1) x += __shfl_xor(x, o);
    if ((d & 63) == 0) red[d >> 6] = x;
    __syncthreads();
    float mu = 0.f;
    #pragma unroll
    for (int i = 0; i < 8; i++) mu += red[i];
    mu *= (1.f / 512.f);
    __syncthreads();
    float c = hn - mu;
    x = c * c;
    for (int o = 32; o; o >>= 1) x += __shfl_xor(x, o);
    if ((d & 63) == 0) red[d >> 6] = x;
    __syncthreads();
    float var = 0.f;
    #pragma unroll
    for (int i = 0; i < 8; i++) var += red[i];
    var *= (1.f / 512.f);
    float hl = c * rsqrtf(var + 1e-5f) * ln_g[d] + ln_b[d];
    h[b * 512 + d] = hl;
    h_all[(size_t)(t * 64 + b) * 512 + d] = hl;
}

extern "C" void kernel_launch(void* const* d_in, const int* in_sizes, int n_in,
                              void* d_out, int out_size, void* d_ws, size_t ws_size,
                              hipStream_t stream) {
    const float* enc     = (const float*)d_in[0];
    const int*   caps    = (const int*)d_in[1];
    const float* emb_w   = (const float*)d_in[2];
    const float* Wq      = (const float*)d_in[3];
    const float* bq      = (const float*)d_in[4];
    const float* Wk      = (const float*)d_in[5];
    const float* bk      = (const float*)d_in[6];
    const float* Wv      = (const float*)d_in[7];
    const float* bv      = (const float*)d_in[8];
    const float* Wo      = (const float*)d_in[9];
    const float* bo      = (const float*)d_in[10];
    const float* init_w  = (const float*)d_in[11];
    const float* init_b  = (const float*)d_in[12];
    const float* W_ih    = (const float*)d_in[13];
    const float* b_ih    = (const float*)d_in[14];
    const float* W_hh    = (const float*)d_in[15];
    const float* b_hh    = (const float*)d_in[16];
    const float* ln_g    = (const float*)d_in[17];
    const float* ln_b    = (const float*)d_in[18];
    const float* fc_w    = (const float*)d_in[19];
    const float* fc_b    = (const float*)d_in[20];

    float* ws     = (float*)d_ws;
    float* me     = ws + OFF_ME;
    float* embAll = ws + OFF_EMBALL;
    float* ktb    = ws + OFF_KT;
    float* vb     = ws + OFF_V;
    float* giE    = ws + OFF_GIE;
    float* Wfused = ws + OFF_WF;
    float* gibo   = ws + OFF_GIBO;
    float* h      = ws + OFF_H;
    float* h_all  = ws + OFF_HALL;
    float* h0p    = ws + OFF_H0P;
    float* qp     = ws + OFF_QP;
    float* ghp    = ws + OFF_GHP;
    float* gip    = ws + OFF_GIP;
    float* ctx    = ws + OFF_CTX;

    float* out    = (float*)d_out;           // [64][20][32000]
    float* attw   = out + 40960000;          // [64][20][49]

    // ---- one-time precompute ----
    hipLaunchKernelGGL(mean_kernel, dim3(512), dim3(256), 0, stream, enc, me);
    hipLaunchKernelGGL(init_kernel, dim3(2560), dim3(256), 0, stream, caps, emb_w, embAll, attw);
    hipLaunchKernelGGL(gibo_kernel, dim3(1536), dim3(256), 0, stream, W_ih, bo, gibo);
    hipLaunchKernelGGL(gemm_splitk, dim3(8, 8), dim3(256), 0, stream,
                       me, 2048, init_w, 2048, 1, h0p, 512, 256);
    hipLaunchKernelGGL(reduce_h0, dim3(128), dim3(256), 0, stream, h0p, init_b, h);
    hipLaunchKernelGGL(gemm128, dim3(4, 25), dim3(256), 0, stream,
                       enc, 2048, 3136, Wk, 512, 0, bk, ktb, 0, 2048, 2);
    hipLaunchKernelGGL(gemm128, dim3(4, 25), dim3(256), 0, stream,
                       enc, 2048, 3136, Wv, 512, 0, bv, vb, 512, 2048, 0);
    hipLaunchKernelGGL(gemm128, dim3(12, 10), dim3(256), 0, stream,
                       embAll, 512, 1280, W_ih, 2560, 1, (const float*)nullptr, giE, 1536, 512, 0);
    hipLaunchKernelGGL(gemm128, dim3(12, 4), dim3(256), 0, stream,
                       Wo, 2048, 512, W_ih + 512, 2560, 1, (const float*)nullptr, Wfused, 1536, 2048, 0);

    // ---- recurrence ----
    for (int t = 0; t < TSTEPS; t++) {
        hipLaunchKernelGGL(gemm_splitk, dim3(8, 4), dim3(256), 0, stream,
                           h, 512, Wq, 512, 0, qp, 512, 128);
        hipLaunchKernelGGL(gemm_splitk, dim3(24, 4), dim3(256), 0, stream,
                           h, 512, W_hh, 512, 1, ghp, 1536, 128);
        hipLaunchKernelGGL(attn_kernel, dim3(512), dim3(64), 0, stream,
                           qp, bq, ktb, vb, ctx, attw, t);
        hipLaunchKernelGGL(gemm_splitk, dim3(24, 4), dim3(256), 0, stream,
                           ctx, 512, Wfused, 1536, 0, gip, 1536, 128);
        hipLaunchKernelGGL(gate_ln_kernel, dim3(64), dim3(512), 0, stream,
                           gip, ghp, giE, gibo, b_ih, b_hh, ln_g, ln_b, h, h_all, t);
    }

    // ---- batched logits ----
    hipLaunchKernelGGL(gemm128, dim3(250, 10), dim3(256), 0, stream,
                       h_all, 512, 1280, fc_w, 512, 1, fc_b, out, 32000, 512, 1);
}